// Round 1
// baseline (50.182 us; speedup 1.0000x reference)
//
#include <hip/hip_runtime.h>

#define NPTS 384
#define DIM  256
#define MARGIN 1.0f

// One block per anchor i. Computes d[i,:] = ||x_i - x_j||^2 into LDS,
// builds the same-class d_k list, accumulates
//   num_i = sum_{j: lab[j]!=li} sum_{k: lab[k]==li} max(d_ij + d_ik - MARGIN, 0)
//   cnt_i = (#same-class k) * (#diff-class j)
// and writes per-block partials (no atomics -> deterministic, no init needed).
__global__ __launch_bounds__(256) void triplet_main(const float* __restrict__ x,
                                                    const int* __restrict__ labels,
                                                    float* __restrict__ pnum,
                                                    int* __restrict__ pcnt) {
    const int i   = blockIdx.x;
    const int tid = threadIdx.x;

    __shared__ float xi_s[DIM];     // anchor row
    __shared__ float drow[NPTS];    // d[i, :]
    __shared__ int   lab[NPTS];
    __shared__ float dk_list[NPTS]; // d[i,k] for same-class k
    __shared__ int   nk_sh;
    __shared__ float rnum[256];
    __shared__ int   rcnt[256];

    // stage anchor row + labels
    xi_s[tid] = x[i * DIM + tid];                       // blockDim == DIM == 256
    for (int j = tid; j < NPTS; j += 256) lab[j] = labels[j];
    __syncthreads();

    // d-row: thread j computes ||x_i - x_j||^2 (float4 loads; xi from LDS broadcast)
    const float4* xi4 = (const float4*)xi_s;
    for (int j = tid; j < NPTS; j += 256) {
        const float4* rj = (const float4*)(x + (size_t)j * DIM);
        float acc = 0.f;
        #pragma unroll 16
        for (int e = 0; e < DIM / 4; ++e) {
            float4 a = rj[e];
            float4 b = xi4[e];
            float d0 = a.x - b.x, d1 = a.y - b.y, d2 = a.z - b.z, d3 = a.w - b.w;
            acc += d0 * d0 + d1 * d1 + d2 * d2 + d3 * d3;
        }
        drow[j] = acc;
    }
    __syncthreads();

    const int li = lab[i];

    // deterministic same-class gather (serial on thread 0; ~384 LDS iters, cheap)
    if (tid == 0) {
        int p = 0;
        for (int k = 0; k < NPTS; ++k)
            if (lab[k] == li) dk_list[p++] = drow[k];
        nk_sh = p;
    }
    __syncthreads();
    const int nk = nk_sh;

    // pair accumulation: threads over j (negatives), serial over ~nk positives
    float num = 0.f;
    int   cnt = 0;
    for (int j = tid; j < NPTS; j += 256) {
        if (lab[j] != li) {
            float dj1 = drow[j] - MARGIN;
            for (int t = 0; t < nk; ++t) {
                float h = dj1 + dk_list[t];
                num += (h > 0.f) ? h : 0.f;
            }
            cnt += nk;
        }
    }

    // block tree-reduce (deterministic)
    rnum[tid] = num; rcnt[tid] = cnt;
    __syncthreads();
    for (int s = 128; s > 0; s >>= 1) {
        if (tid < s) { rnum[tid] += rnum[tid + s]; rcnt[tid] += rcnt[tid + s]; }
        __syncthreads();
    }
    if (tid == 0) { pnum[i] = rnum[0]; pcnt[i] = rcnt[0]; }
}

__global__ __launch_bounds__(256) void triplet_finalize(const float* __restrict__ pnum,
                                                        const int* __restrict__ pcnt,
                                                        float* __restrict__ out) {
    __shared__ float rnum[256];
    __shared__ int   rcnt[256];
    const int tid = threadIdx.x;
    float n = 0.f; int c = 0;
    for (int p = tid; p < NPTS; p += 256) { n += pnum[p]; c += pcnt[p]; }
    rnum[tid] = n; rcnt[tid] = c;
    __syncthreads();
    for (int s = 128; s > 0; s >>= 1) {
        if (tid < s) { rnum[tid] += rnum[tid + s]; rcnt[tid] += rcnt[tid + s]; }
        __syncthreads();
    }
    if (tid == 0) out[0] = rnum[0] / (float)rcnt[0];
}

extern "C" void kernel_launch(void* const* d_in, const int* in_sizes, int n_in,
                              void* d_out, int out_size, void* d_ws, size_t ws_size,
                              hipStream_t stream) {
    const float* x      = (const float*)d_in[0];
    const int*   labels = (const int*)d_in[1];
    float*       out    = (float*)d_out;

    float* pnum = (float*)d_ws;
    int*   pcnt = (int*)((char*)d_ws + NPTS * sizeof(float));

    triplet_main<<<NPTS, 256, 0, stream>>>(x, labels, pnum, pcnt);
    triplet_finalize<<<1, 256, 0, stream>>>(pnum, pcnt, out);
}

// Round 2
// 25.253 us; speedup vs baseline: 1.9872x; 1.9872x over previous
//
#include <hip/hip_runtime.h>

#define NPTS   384
#define DIM    256
#define NCHUNK 6            // NPTS / 64
#define SPLIT  4            // j-range splits per anchor
#define JB     (NPTS/SPLIT) // 96 j's per block
#define MAXK   192          // max same-class count (expected ~12, hard-capped)
#define MARGIN 1.0f

// Block (i, s): anchor i, j-slice s.
//   - ballot-compact same-class k indices (parallel, deterministic)
//   - wave-cooperative dots: d[i,k] for pos k, d[i,j] for j in slice
//     (coalesced float4/lane, shfl-xor reduce, anchor in registers)
//   - hinge accumulation over (neg j in slice) x (pos k)
__global__ __launch_bounds__(256) void triplet_main(const float* __restrict__ x,
                                                    const int* __restrict__ labels,
                                                    float* __restrict__ pnum,
                                                    int* __restrict__ pcnt) {
    const int i    = blockIdx.x;
    const int s    = blockIdx.y;
    const int tid  = threadIdx.x;
    const int lane = tid & 63;
    const int wid  = tid >> 6;

    __shared__ int   lab[NPTS];
    __shared__ int   kidx[MAXK];
    __shared__ float dk[MAXK];
    __shared__ float dj[JB];
    __shared__ int   nk_sh;
    __shared__ float wnum[4];
    __shared__ int   wcnt[4];

    for (int j = tid; j < NPTS; j += 256) lab[j] = labels[j];
    __syncthreads();
    const int li = lab[i];

    // parallel compaction of same-class k indices (wave 0, ballot + prefix)
    if (tid < 64) {
        int base = 0;
        for (int c = 0; c < NCHUNK; ++c) {
            const int k = c * 64 + tid;
            const bool m = (lab[k] == li);
            const unsigned long long mask = __ballot(m);
            const int pre = __popcll(mask & ((1ull << tid) - 1ull));
            if (m && (base + pre) < MAXK) kidx[base + pre] = k;
            base += __popcll(mask);
        }
        if (tid == 0) nk_sh = (base > MAXK) ? MAXK : base;
    }
    __syncthreads();
    const int nk = nk_sh;

    // anchor fragment: lane l holds x[i, 4l..4l+3] (whole row across the wave)
    const float4 bx = *(const float4*)(x + (size_t)i * DIM + lane * 4);

    // wave-cooperative dots: first nk targets are pos-k rows, then the j-slice
    const int ndot = nk + JB;
    for (int t = wid; t < ndot; t += 4) {
        const int row = (t < nk) ? kidx[t] : (s * JB + (t - nk));
        const float4 a = *(const float4*)(x + (size_t)row * DIM + lane * 4);
        const float d0 = a.x - bx.x, d1 = a.y - bx.y, d2 = a.z - bx.z, d3 = a.w - bx.w;
        float p = d0 * d0 + d1 * d1 + d2 * d2 + d3 * d3;
        #pragma unroll
        for (int m = 1; m < 64; m <<= 1) p += __shfl_xor(p, m, 64);
        if (lane == 0) {
            if (t < nk) dk[t] = p;
            else        dj[t - nk] = p;
        }
    }
    __syncthreads();

    // hinge accumulation: thread tid<96 owns j = s*96+tid
    float num = 0.f;
    int   cnt = 0;
    if (tid < JB) {
        const int j = s * JB + tid;
        if (lab[j] != li) {
            const float b = dj[tid] - MARGIN;
            for (int t = 0; t < nk; ++t) {
                const float h = b + dk[t];
                num += (h > 0.f) ? h : 0.f;
            }
            cnt = nk;
        }
    }
    // waves 0,1 hold all values; shfl reduce then combine
    if (tid < 128) {
        #pragma unroll
        for (int m = 1; m < 64; m <<= 1) {
            num += __shfl_xor(num, m, 64);
            cnt += __shfl_xor(cnt, m, 64);
        }
        if (lane == 0) { wnum[wid] = num; wcnt[wid] = cnt; }
    }
    __syncthreads();
    if (tid == 0) {
        const int pb = s * NPTS + i;
        pnum[pb] = wnum[0] + wnum[1];
        pcnt[pb] = wcnt[0] + wcnt[1];
    }
}

__global__ __launch_bounds__(256) void triplet_finalize(const float* __restrict__ pnum,
                                                        const int* __restrict__ pcnt,
                                                        float* __restrict__ out) {
    const int tid = threadIdx.x, lane = tid & 63, wid = tid >> 6;
    __shared__ float wnum[4];
    __shared__ int   wcnt[4];
    float n = 0.f;
    int   c = 0;
    for (int p = tid; p < NPTS * SPLIT; p += 256) { n += pnum[p]; c += pcnt[p]; }
    #pragma unroll
    for (int m = 1; m < 64; m <<= 1) {
        n += __shfl_xor(n, m, 64);
        c += __shfl_xor(c, m, 64);
    }
    if (lane == 0) { wnum[wid] = n; wcnt[wid] = c; }
    __syncthreads();
    if (tid == 0)
        out[0] = (wnum[0] + wnum[1] + wnum[2] + wnum[3]) /
                 (float)(wcnt[0] + wcnt[1] + wcnt[2] + wcnt[3]);
}

extern "C" void kernel_launch(void* const* d_in, const int* in_sizes, int n_in,
                              void* d_out, int out_size, void* d_ws, size_t ws_size,
                              hipStream_t stream) {
    const float* x      = (const float*)d_in[0];
    const int*   labels = (const int*)d_in[1];
    float*       out    = (float*)d_out;

    float* pnum = (float*)d_ws;
    int*   pcnt = (int*)((char*)d_ws + NPTS * SPLIT * sizeof(float));

    dim3 grid(NPTS, SPLIT);
    triplet_main<<<grid, 256, 0, stream>>>(x, labels, pnum, pcnt);
    triplet_finalize<<<1, 256, 0, stream>>>(pnum, pcnt, out);
}